// Round 1
// baseline (1472.880 us; speedup 1.0000x reference)
//
#include <hip/hip_runtime.h>
#include <hip/hip_bf16.h>

#define H 128
#define DOUT 32
#define NGRAPH 64
#define MM_ROWS 64

// ---------------- CSR build ----------------

__global__ __launch_bounds__(256) void hist_edge_kernel(const int* __restrict__ dst, int E,
                                                        int* __restrict__ deg) {
    int e = blockIdx.x * 256 + threadIdx.x;
    if (e < E) atomicAdd(&deg[dst[e]], 1);
}

__global__ __launch_bounds__(256) void hist_batch_kernel(const int* __restrict__ batch, int N,
                                                         int* __restrict__ cnt) {
    int i = blockIdx.x * 256 + threadIdx.x;
    if (i < N) atomicAdd(&cnt[batch[i]], 1);
}

// block covers 1024 nodes; 256 threads x 4 elems
__global__ __launch_bounds__(256) void scan_phase1(const int* __restrict__ deg, int N,
                                                   int* __restrict__ bsum) {
    __shared__ int sd[256];
    int t = threadIdx.x;
    int base = blockIdx.x * 1024 + t * 4;
    int s = 0;
#pragma unroll
    for (int j = 0; j < 4; ++j)
        if (base + j < N) s += deg[base + j];
    sd[t] = s;
    __syncthreads();
    for (int off = 128; off > 0; off >>= 1) {
        if (t < off) sd[t] += sd[t + off];
        __syncthreads();
    }
    if (t == 0) bsum[blockIdx.x] = sd[0];
}

// serial exclusive scan of block sums (nb ~ 98, trivial); converts bsum in place
__global__ void scan_phase2(int* bsum, int nb, int* __restrict__ row_ptr, int N, int E) {
    if (threadIdx.x == 0) {
        int run = 0;
        for (int i = 0; i < nb; ++i) {
            int v = bsum[i];
            bsum[i] = run;
            run += v;
        }
        row_ptr[N] = E;
    }
}

__global__ __launch_bounds__(256) void scan_phase3(const int* __restrict__ deg,
                                                   const int* __restrict__ boff, int N,
                                                   int* __restrict__ row_ptr) {
    __shared__ int sd[256];
    int t = threadIdx.x;
    int base = blockIdx.x * 1024 + t * 4;
    int v[4];
    int s = 0;
#pragma unroll
    for (int j = 0; j < 4; ++j) {
        v[j] = (base + j < N) ? deg[base + j] : 0;
        s += v[j];
    }
    sd[t] = s;
    __syncthreads();
    // Hillis-Steele inclusive scan over thread sums
    for (int off = 1; off < 256; off <<= 1) {
        int x = (t >= off) ? sd[t - off] : 0;
        __syncthreads();
        sd[t] += x;
        __syncthreads();
    }
    int run = boff[blockIdx.x] + sd[t] - s;  // exclusive prefix for this thread
#pragma unroll
    for (int j = 0; j < 4; ++j)
        if (base + j < N) {
            row_ptr[base + j] = run;
            run += v[j];
        }
}

__global__ __launch_bounds__(256) void init_node_kernel(const int* __restrict__ deg,
                                                        const int* __restrict__ row_ptr,
                                                        float* __restrict__ dinv,
                                                        int* __restrict__ fill, int N) {
    int i = blockIdx.x * 256 + threadIdx.x;
    if (i < N) {
        dinv[i] = rsqrtf(1.0f + (float)deg[i]);
        fill[i] = row_ptr[i];
    }
}

__global__ void gscan_kernel(const int* __restrict__ cnt, int* __restrict__ gstart) {
    if (threadIdx.x == 0) {
        int run = 0;
        for (int g = 0; g < NGRAPH; ++g) {
            gstart[g] = run;
            run += cnt[g];
        }
        gstart[NGRAPH] = run;
    }
}

__global__ __launch_bounds__(256) void fill_csr_kernel(const int* __restrict__ src,
                                                       const int* __restrict__ dst, int E,
                                                       int* __restrict__ fill,
                                                       int* __restrict__ col) {
    int e = blockIdx.x * 256 + threadIdx.x;
    if (e < E) {
        int d = dst[e];
        int pos = atomicAdd(&fill[d], 1);
        col[pos] = src[e];
    }
}

// ---------------- compute ----------------

// Out[row] = (X[row] @ W) * dinv[row];  X:[M,128], W:[128,128]
__global__ __launch_bounds__(256) void mm_scale_kernel(const float* __restrict__ X,
                                                       const float* __restrict__ W,
                                                       const float* __restrict__ dinv,
                                                       float* __restrict__ Out, int M) {
    __shared__ float xs[128 * 65];  // xs[k*65 + m] = X[row0+m][k], +1 pad vs 64
    int tid = threadIdx.x;
    int row0 = blockIdx.x * MM_ROWS;
    int c = tid & 31, rl = tid >> 5;
#pragma unroll
    for (int p = 0; p < MM_ROWS; p += 8) {
        int m = p + rl;
        int row = row0 + m;
        float4 v = make_float4(0.f, 0.f, 0.f, 0.f);
        if (row < M) v = *reinterpret_cast<const float4*>(X + (size_t)row * H + c * 4);
        xs[(4 * c + 0) * 65 + m] = v.x;
        xs[(4 * c + 1) * 65 + m] = v.y;
        xs[(4 * c + 2) * 65 + m] = v.z;
        xs[(4 * c + 3) * 65 + m] = v.w;
    }
    __syncthreads();
    int tx = tid & 31;  // cols 4*tx .. 4*tx+3
    int ty = tid >> 5;  // rows ty*8 .. ty*8+7
    float acc[8][4];
#pragma unroll
    for (int i = 0; i < 8; ++i)
#pragma unroll
        for (int j = 0; j < 4; ++j) acc[i][j] = 0.f;
#pragma unroll 4
    for (int k = 0; k < 128; ++k) {
        float4 w = *reinterpret_cast<const float4*>(W + k * H + tx * 4);
        float xv[8];
#pragma unroll
        for (int i = 0; i < 8; ++i) xv[i] = xs[k * 65 + ty * 8 + i];
#pragma unroll
        for (int i = 0; i < 8; ++i) {
            acc[i][0] = fmaf(xv[i], w.x, acc[i][0]);
            acc[i][1] = fmaf(xv[i], w.y, acc[i][1]);
            acc[i][2] = fmaf(xv[i], w.z, acc[i][2]);
            acc[i][3] = fmaf(xv[i], w.w, acc[i][3]);
        }
    }
#pragma unroll
    for (int i = 0; i < 8; ++i) {
        int row = row0 + ty * 8 + i;
        if (row < M) {
            float sc = dinv[row];
            float4 o = make_float4(acc[i][0] * sc, acc[i][1] * sc, acc[i][2] * sc,
                                   acc[i][3] * sc);
            *reinterpret_cast<float4*>(Out + (size_t)row * H + tx * 4) = o;
        }
    }
}

// Out[i] = relu(dinv[i] * (sum_{e in CSR row i} A[col[e]] + A[i]) + bias)
__global__ __launch_bounds__(128) void agg_kernel(const float* __restrict__ A,
                                                  const int* __restrict__ row_ptr,
                                                  const int* __restrict__ col,
                                                  const float* __restrict__ dinv,
                                                  const float* __restrict__ bias,
                                                  float* __restrict__ Out, int N) {
    int i = blockIdx.x;
    int f = threadIdx.x;
    int s = row_ptr[i], e = row_ptr[i + 1];
    float acc = A[(size_t)i * H + f];  // self-loop term (dinv factored out)
    int j = s;
    for (; j + 4 <= e; j += 4) {
        int c0 = col[j], c1 = col[j + 1], c2 = col[j + 2], c3 = col[j + 3];
        float a0 = A[(size_t)c0 * H + f];
        float a1 = A[(size_t)c1 * H + f];
        float a2 = A[(size_t)c2 * H + f];
        float a3 = A[(size_t)c3 * H + f];
        acc += a0;
        acc += a1;
        acc += a2;
        acc += a3;
    }
    for (; j < e; ++j) acc += A[(size_t)col[j] * H + f];
    float o = fmaf(dinv[i], acc, bias[f]);
    Out[(size_t)i * H + f] = fmaxf(o, 0.0f);
}

__global__ __launch_bounds__(128) void pool_kernel(const float* __restrict__ Bm,
                                                   const int* __restrict__ gstart,
                                                   float* __restrict__ g) {
    int gr = blockIdx.x, f = threadIdx.x;
    int s = gstart[gr], e = gstart[gr + 1];
    float acc = 0.f;
    for (int n = s; n < e; ++n) acc += Bm[(size_t)n * H + f];
    g[gr * H + f] = acc / fmaxf((float)(e - s), 1.f);
}

__global__ __launch_bounds__(128) void head_kernel(const float* __restrict__ g,
                                                   const float* __restrict__ fW1,
                                                   const float* __restrict__ fb1,
                                                   const float* __restrict__ fW2,
                                                   const float* __restrict__ fb2,
                                                   float* __restrict__ out) {
    __shared__ float gv[H], hid[H], lg[DOUT];
    int gr = blockIdx.x, f = threadIdx.x;
    gv[f] = g[gr * H + f];
    __syncthreads();
    float acc = fb1[f];
    for (int k = 0; k < H; ++k) acc = fmaf(gv[k], fW1[k * H + f], acc);
    hid[f] = fmaxf(acc, 0.f);
    __syncthreads();
    if (f < DOUT) {
        float a = fb2[f];
        for (int k = 0; k < H; ++k) a = fmaf(hid[k], fW2[k * DOUT + f], a);
        lg[f] = a;
    }
    __syncthreads();
    if (f < DOUT) {
        float mx = -1e30f;
        for (int j = 0; j < DOUT; ++j) mx = fmaxf(mx, lg[j]);
        float ssum = 0.f;
        for (int j = 0; j < DOUT; ++j) ssum += expf(lg[j] - mx);
        out[gr * DOUT + f] = expf(lg[f] - mx) / ssum;
    }
}

// ---------------- launch ----------------

extern "C" void kernel_launch(void* const* d_in, const int* in_sizes, int n_in,
                              void* d_out, int out_size, void* d_ws, size_t ws_size,
                              hipStream_t stream) {
    const float* x = (const float*)d_in[0];
    const int* edge = (const int*)d_in[1];
    const int* batch = (const int*)d_in[2];
    const float* W1 = (const float*)d_in[3];
    const float* b1 = (const float*)d_in[4];
    const float* W2 = (const float*)d_in[5];
    const float* b2 = (const float*)d_in[6];
    const float* fW1 = (const float*)d_in[7];
    const float* fb1 = (const float*)d_in[8];
    const float* fW2 = (const float*)d_in[9];
    const float* fb2 = (const float*)d_in[10];
    float* out = (float*)d_out;

    int N = in_sizes[0] / H;
    int E = in_sizes[1] / 2;
    const int* srcI = edge;
    const int* dstI = edge + E;

    char* ws = (char*)d_ws;
    size_t off = 0;
    auto alloc = [&](size_t bytes) {
        void* p = ws + off;
        off = (off + bytes + 255) & ~(size_t)255;
        return p;
    };
    int* deg = (int*)alloc((size_t)N * 4);
    int* row_ptr = (int*)alloc((size_t)(N + 1) * 4);
    int* fill = (int*)alloc((size_t)N * 4);
    int* col = (int*)alloc((size_t)E * 4);
    float* dinv = (float*)alloc((size_t)N * 4);
    int* bsum = (int*)alloc(4096);
    int* cntg = (int*)alloc(256);
    int* gstart = (int*)alloc(512);
    float* gmat = (float*)alloc((size_t)NGRAPH * H * 4);
    float* A = (float*)alloc((size_t)N * H * 4);
    float* Bm = (float*)alloc((size_t)N * H * 4);
    (void)ws_size;

    hipMemsetAsync(deg, 0, (size_t)N * 4, stream);
    hipMemsetAsync(cntg, 0, 256, stream);

    int nb = (N + 1023) / 1024;
    hist_edge_kernel<<<(E + 255) / 256, 256, 0, stream>>>(dstI, E, deg);
    hist_batch_kernel<<<(N + 255) / 256, 256, 0, stream>>>(batch, N, cntg);
    scan_phase1<<<nb, 256, 0, stream>>>(deg, N, bsum);
    scan_phase2<<<1, 1, 0, stream>>>(bsum, nb, row_ptr, N, E);
    scan_phase3<<<nb, 256, 0, stream>>>(deg, bsum, N, row_ptr);
    init_node_kernel<<<(N + 255) / 256, 256, 0, stream>>>(deg, row_ptr, dinv, fill, N);
    gscan_kernel<<<1, 1, 0, stream>>>(cntg, gstart);
    fill_csr_kernel<<<(E + 255) / 256, 256, 0, stream>>>(srcI, dstI, E, fill, col);

    int mmblocks = (N + MM_ROWS - 1) / MM_ROWS;
    mm_scale_kernel<<<mmblocks, 256, 0, stream>>>(x, W1, dinv, A, N);
    agg_kernel<<<N, 128, 0, stream>>>(A, row_ptr, col, dinv, b1, Bm, N);
    mm_scale_kernel<<<mmblocks, 256, 0, stream>>>(Bm, W2, dinv, A, N);
    agg_kernel<<<N, 128, 0, stream>>>(A, row_ptr, col, dinv, b2, Bm, N);
    pool_kernel<<<NGRAPH, 128, 0, stream>>>(Bm, gstart, gmat);
    head_kernel<<<NGRAPH, 128, 0, stream>>>(gmat, fW1, fb1, fW2, fb2, out);
}

// Round 2
// 953.398 us; speedup vs baseline: 1.5449x; 1.5449x over previous
//
#include <hip/hip_runtime.h>
#include <hip/hip_bf16.h>

#define H 128
#define DOUT 32
#define NGRAPH 64
#define MM_ROWS 64

// ---------------- CSR build ----------------

__global__ __launch_bounds__(256) void hist_edge_kernel(const int* __restrict__ dst, int E,
                                                        int* __restrict__ deg) {
    int e = blockIdx.x * 256 + threadIdx.x;
    if (e < E) atomicAdd(&deg[dst[e]], 1);
}

// batch is sorted: gstart[g] = first index i with batch[i] >= g (g in [0,NGRAPH]).
// Boundary detection — no atomics.
__global__ __launch_bounds__(256) void batch_bounds_kernel(const int* __restrict__ batch,
                                                           int N, int* __restrict__ gstart) {
    int i = blockIdx.x * 256 + threadIdx.x;
    if (i < N) {
        int b = batch[i];
        int bp = (i == 0) ? -1 : batch[i - 1];
        for (int g = bp + 1; g <= b; ++g) gstart[g] = i;
        if (i == N - 1)
            for (int g = b + 1; g <= NGRAPH; ++g) gstart[g] = N;
    }
}

// block covers 1024 nodes; 256 threads x 4 elems
__global__ __launch_bounds__(256) void scan_phase1(const int* __restrict__ deg, int N,
                                                   int* __restrict__ bsum) {
    __shared__ int sd[256];
    int t = threadIdx.x;
    int base = blockIdx.x * 1024 + t * 4;
    int s = 0;
#pragma unroll
    for (int j = 0; j < 4; ++j)
        if (base + j < N) s += deg[base + j];
    sd[t] = s;
    __syncthreads();
    for (int off = 128; off > 0; off >>= 1) {
        if (t < off) sd[t] += sd[t + off];
        __syncthreads();
    }
    if (t == 0) bsum[blockIdx.x] = sd[0];
}

// serial exclusive scan of block sums (nb ~ 98, trivial); converts bsum in place
__global__ void scan_phase2(int* bsum, int nb, int* __restrict__ row_ptr, int N, int E) {
    if (threadIdx.x == 0) {
        int run = 0;
        for (int i = 0; i < nb; ++i) {
            int v = bsum[i];
            bsum[i] = run;
            run += v;
        }
        row_ptr[N] = E;
    }
}

__global__ __launch_bounds__(256) void scan_phase3(const int* __restrict__ deg,
                                                   const int* __restrict__ boff, int N,
                                                   int* __restrict__ row_ptr) {
    __shared__ int sd[256];
    int t = threadIdx.x;
    int base = blockIdx.x * 1024 + t * 4;
    int v[4];
    int s = 0;
#pragma unroll
    for (int j = 0; j < 4; ++j) {
        v[j] = (base + j < N) ? deg[base + j] : 0;
        s += v[j];
    }
    sd[t] = s;
    __syncthreads();
    // Hillis-Steele inclusive scan over thread sums
    for (int off = 1; off < 256; off <<= 1) {
        int x = (t >= off) ? sd[t - off] : 0;
        __syncthreads();
        sd[t] += x;
        __syncthreads();
    }
    int run = boff[blockIdx.x] + sd[t] - s;  // exclusive prefix for this thread
#pragma unroll
    for (int j = 0; j < 4; ++j)
        if (base + j < N) {
            row_ptr[base + j] = run;
            run += v[j];
        }
}

__global__ __launch_bounds__(256) void init_node_kernel(const int* __restrict__ deg,
                                                        const int* __restrict__ row_ptr,
                                                        float* __restrict__ dinv,
                                                        int* __restrict__ fill, int N) {
    int i = blockIdx.x * 256 + threadIdx.x;
    if (i < N) {
        dinv[i] = rsqrtf(1.0f + (float)deg[i]);
        fill[i] = row_ptr[i];
    }
}

__global__ __launch_bounds__(256) void fill_csr_kernel(const int* __restrict__ src,
                                                       const int* __restrict__ dst, int E,
                                                       int* __restrict__ fill,
                                                       int* __restrict__ col) {
    int e = blockIdx.x * 256 + threadIdx.x;
    if (e < E) {
        int d = dst[e];
        int pos = atomicAdd(&fill[d], 1);
        col[pos] = src[e];
    }
}

// ---------------- compute ----------------

// Out[row] = (X[row] @ W) * dinv[row];  X:[M,128], W:[128,128]
__global__ __launch_bounds__(256) void mm_scale_kernel(const float* __restrict__ X,
                                                       const float* __restrict__ W,
                                                       const float* __restrict__ dinv,
                                                       float* __restrict__ Out, int M) {
    __shared__ float xs[128 * 65];  // xs[k*65 + m] = X[row0+m][k], +1 pad vs 64
    int tid = threadIdx.x;
    int row0 = blockIdx.x * MM_ROWS;
    int c = tid & 31, rl = tid >> 5;
#pragma unroll
    for (int p = 0; p < MM_ROWS; p += 8) {
        int m = p + rl;
        int row = row0 + m;
        float4 v = make_float4(0.f, 0.f, 0.f, 0.f);
        if (row < M) v = *reinterpret_cast<const float4*>(X + (size_t)row * H + c * 4);
        xs[(4 * c + 0) * 65 + m] = v.x;
        xs[(4 * c + 1) * 65 + m] = v.y;
        xs[(4 * c + 2) * 65 + m] = v.z;
        xs[(4 * c + 3) * 65 + m] = v.w;
    }
    __syncthreads();
    int tx = tid & 31;  // cols 4*tx .. 4*tx+3
    int ty = tid >> 5;  // rows ty*8 .. ty*8+7
    float acc[8][4];
#pragma unroll
    for (int i = 0; i < 8; ++i)
#pragma unroll
        for (int j = 0; j < 4; ++j) acc[i][j] = 0.f;
#pragma unroll 4
    for (int k = 0; k < 128; ++k) {
        float4 w = *reinterpret_cast<const float4*>(W + k * H + tx * 4);
        float xv[8];
#pragma unroll
        for (int i = 0; i < 8; ++i) xv[i] = xs[k * 65 + ty * 8 + i];
#pragma unroll
        for (int i = 0; i < 8; ++i) {
            acc[i][0] = fmaf(xv[i], w.x, acc[i][0]);
            acc[i][1] = fmaf(xv[i], w.y, acc[i][1]);
            acc[i][2] = fmaf(xv[i], w.z, acc[i][2]);
            acc[i][3] = fmaf(xv[i], w.w, acc[i][3]);
        }
    }
#pragma unroll
    for (int i = 0; i < 8; ++i) {
        int row = row0 + ty * 8 + i;
        if (row < M) {
            float sc = dinv[row];
            float4 o = make_float4(acc[i][0] * sc, acc[i][1] * sc, acc[i][2] * sc,
                                   acc[i][3] * sc);
            *reinterpret_cast<float4*>(Out + (size_t)row * H + tx * 4) = o;
        }
    }
}

// Out[i] = relu(dinv[i] * (sum_{e in CSR row i} A[col[e]] + A[i]) + bias)
__global__ __launch_bounds__(128) void agg_kernel(const float* __restrict__ A,
                                                  const int* __restrict__ row_ptr,
                                                  const int* __restrict__ col,
                                                  const float* __restrict__ dinv,
                                                  const float* __restrict__ bias,
                                                  float* __restrict__ Out, int N) {
    int i = blockIdx.x;
    int f = threadIdx.x;
    int s = row_ptr[i], e = row_ptr[i + 1];
    float acc = A[(size_t)i * H + f];  // self-loop term (dinv factored out)
    int j = s;
    for (; j + 4 <= e; j += 4) {
        int c0 = col[j], c1 = col[j + 1], c2 = col[j + 2], c3 = col[j + 3];
        float a0 = A[(size_t)c0 * H + f];
        float a1 = A[(size_t)c1 * H + f];
        float a2 = A[(size_t)c2 * H + f];
        float a3 = A[(size_t)c3 * H + f];
        acc += a0;
        acc += a1;
        acc += a2;
        acc += a3;
    }
    for (; j < e; ++j) acc += A[(size_t)col[j] * H + f];
    float o = fmaf(dinv[i], acc, bias[f]);
    Out[(size_t)i * H + f] = fmaxf(o, 0.0f);
}

__global__ __launch_bounds__(128) void pool_kernel(const float* __restrict__ Bm,
                                                   const int* __restrict__ gstart,
                                                   float* __restrict__ g) {
    int gr = blockIdx.x, f = threadIdx.x;
    int s = gstart[gr], e = gstart[gr + 1];
    float acc = 0.f;
    for (int n = s; n < e; ++n) acc += Bm[(size_t)n * H + f];
    g[gr * H + f] = acc / fmaxf((float)(e - s), 1.f);
}

__global__ __launch_bounds__(128) void head_kernel(const float* __restrict__ g,
                                                   const float* __restrict__ fW1,
                                                   const float* __restrict__ fb1,
                                                   const float* __restrict__ fW2,
                                                   const float* __restrict__ fb2,
                                                   float* __restrict__ out) {
    __shared__ float gv[H], hid[H], lg[DOUT];
    int gr = blockIdx.x, f = threadIdx.x;
    gv[f] = g[gr * H + f];
    __syncthreads();
    float acc = fb1[f];
    for (int k = 0; k < H; ++k) acc = fmaf(gv[k], fW1[k * H + f], acc);
    hid[f] = fmaxf(acc, 0.f);
    __syncthreads();
    if (f < DOUT) {
        float a = fb2[f];
        for (int k = 0; k < H; ++k) a = fmaf(hid[k], fW2[k * DOUT + f], a);
        lg[f] = a;
    }
    __syncthreads();
    if (f < DOUT) {
        float mx = -1e30f;
        for (int j = 0; j < DOUT; ++j) mx = fmaxf(mx, lg[j]);
        float ssum = 0.f;
        for (int j = 0; j < DOUT; ++j) ssum += expf(lg[j] - mx);
        out[gr * DOUT + f] = expf(lg[f] - mx) / ssum;
    }
}

// ---------------- launch ----------------

extern "C" void kernel_launch(void* const* d_in, const int* in_sizes, int n_in,
                              void* d_out, int out_size, void* d_ws, size_t ws_size,
                              hipStream_t stream) {
    const float* x = (const float*)d_in[0];
    const int* edge = (const int*)d_in[1];
    const int* batch = (const int*)d_in[2];
    const float* W1 = (const float*)d_in[3];
    const float* b1 = (const float*)d_in[4];
    const float* W2 = (const float*)d_in[5];
    const float* b2 = (const float*)d_in[6];
    const float* fW1 = (const float*)d_in[7];
    const float* fb1 = (const float*)d_in[8];
    const float* fW2 = (const float*)d_in[9];
    const float* fb2 = (const float*)d_in[10];
    float* out = (float*)d_out;

    int N = in_sizes[0] / H;
    int E = in_sizes[1] / 2;
    const int* srcI = edge;
    const int* dstI = edge + E;

    char* ws = (char*)d_ws;
    size_t off = 0;
    auto alloc = [&](size_t bytes) {
        void* p = ws + off;
        off = (off + bytes + 255) & ~(size_t)255;
        return p;
    };
    int* deg = (int*)alloc((size_t)N * 4);
    int* row_ptr = (int*)alloc((size_t)(N + 1) * 4);
    int* fill = (int*)alloc((size_t)N * 4);
    int* col = (int*)alloc((size_t)E * 4);
    float* dinv = (float*)alloc((size_t)N * 4);
    int* bsum = (int*)alloc(4096);
    int* gstart = (int*)alloc(512);
    float* gmat = (float*)alloc((size_t)NGRAPH * H * 4);
    float* A = (float*)alloc((size_t)N * H * 4);
    float* Bm = (float*)alloc((size_t)N * H * 4);
    (void)ws_size;

    hipMemsetAsync(deg, 0, (size_t)N * 4, stream);

    int nb = (N + 1023) / 1024;
    hist_edge_kernel<<<(E + 255) / 256, 256, 0, stream>>>(dstI, E, deg);
    batch_bounds_kernel<<<(N + 255) / 256, 256, 0, stream>>>(batch, N, gstart);
    scan_phase1<<<nb, 256, 0, stream>>>(deg, N, bsum);
    scan_phase2<<<1, 1, 0, stream>>>(bsum, nb, row_ptr, N, E);
    scan_phase3<<<nb, 256, 0, stream>>>(deg, bsum, N, row_ptr);
    init_node_kernel<<<(N + 255) / 256, 256, 0, stream>>>(deg, row_ptr, dinv, fill, N);
    fill_csr_kernel<<<(E + 255) / 256, 256, 0, stream>>>(srcI, dstI, E, fill, col);

    int mmblocks = (N + MM_ROWS - 1) / MM_ROWS;
    mm_scale_kernel<<<mmblocks, 256, 0, stream>>>(x, W1, dinv, A, N);
    agg_kernel<<<N, 128, 0, stream>>>(A, row_ptr, col, dinv, b1, Bm, N);
    mm_scale_kernel<<<mmblocks, 256, 0, stream>>>(Bm, W2, dinv, A, N);
    agg_kernel<<<N, 128, 0, stream>>>(A, row_ptr, col, dinv, b2, Bm, N);
    pool_kernel<<<NGRAPH, 128, 0, stream>>>(Bm, gstart, gmat);
    head_kernel<<<NGRAPH, 128, 0, stream>>>(gmat, fW1, fb1, fW2, fb2, out);
}

// Round 3
// 601.144 us; speedup vs baseline: 2.4501x; 1.5860x over previous
//
#include <hip/hip_runtime.h>
#include <hip/hip_bf16.h>

#define H 128
#define DOUT 32
#define NGRAPH 64
#define MM_ROWS 64
#define PCHUNK 128

// ---------------- CSR build ----------------

__global__ __launch_bounds__(256) void hist_edge_kernel(const int* __restrict__ dst, int E,
                                                        int* __restrict__ deg) {
    int e = blockIdx.x * 256 + threadIdx.x;
    if (e < E) atomicAdd(&deg[dst[e]], 1);
}

// batch is sorted: gstart[g] = first index i with batch[i] >= g (g in [0,NGRAPH]).
// Boundary detection — no atomics.
__global__ __launch_bounds__(256) void batch_bounds_kernel(const int* __restrict__ batch,
                                                           int N, int* __restrict__ gstart) {
    int i = blockIdx.x * 256 + threadIdx.x;
    if (i < N) {
        int b = batch[i];
        int bp = (i == 0) ? -1 : batch[i - 1];
        for (int g = bp + 1; g <= b; ++g) gstart[g] = i;
        if (i == N - 1)
            for (int g = b + 1; g <= NGRAPH; ++g) gstart[g] = N;
    }
}

// block covers 1024 nodes; 256 threads x 4 elems
__global__ __launch_bounds__(256) void scan_phase1(const int* __restrict__ deg, int N,
                                                   int* __restrict__ bsum) {
    __shared__ int sd[256];
    int t = threadIdx.x;
    int base = blockIdx.x * 1024 + t * 4;
    int s = 0;
#pragma unroll
    for (int j = 0; j < 4; ++j)
        if (base + j < N) s += deg[base + j];
    sd[t] = s;
    __syncthreads();
    for (int off = 128; off > 0; off >>= 1) {
        if (t < off) sd[t] += sd[t + off];
        __syncthreads();
    }
    if (t == 0) bsum[blockIdx.x] = sd[0];
}

// serial exclusive scan of block sums (nb ~ 98, trivial); converts bsum in place
__global__ void scan_phase2(int* bsum, int nb, int* __restrict__ row_ptr, int N, int E) {
    if (threadIdx.x == 0) {
        int run = 0;
        for (int i = 0; i < nb; ++i) {
            int v = bsum[i];
            bsum[i] = run;
            run += v;
        }
        row_ptr[N] = E;
    }
}

__global__ __launch_bounds__(256) void scan_phase3(const int* __restrict__ deg,
                                                   const int* __restrict__ boff, int N,
                                                   int* __restrict__ row_ptr) {
    __shared__ int sd[256];
    int t = threadIdx.x;
    int base = blockIdx.x * 1024 + t * 4;
    int v[4];
    int s = 0;
#pragma unroll
    for (int j = 0; j < 4; ++j) {
        v[j] = (base + j < N) ? deg[base + j] : 0;
        s += v[j];
    }
    sd[t] = s;
    __syncthreads();
    // Hillis-Steele inclusive scan over thread sums
    for (int off = 1; off < 256; off <<= 1) {
        int x = (t >= off) ? sd[t - off] : 0;
        __syncthreads();
        sd[t] += x;
        __syncthreads();
    }
    int run = boff[blockIdx.x] + sd[t] - s;  // exclusive prefix for this thread
#pragma unroll
    for (int j = 0; j < 4; ++j)
        if (base + j < N) {
            row_ptr[base + j] = run;
            run += v[j];
        }
}

__global__ __launch_bounds__(256) void init_node_kernel(const int* __restrict__ deg,
                                                        const int* __restrict__ row_ptr,
                                                        float* __restrict__ dinv,
                                                        int* __restrict__ fill, int N) {
    int i = blockIdx.x * 256 + threadIdx.x;
    if (i < N) {
        dinv[i] = rsqrtf(1.0f + (float)deg[i]);
        fill[i] = row_ptr[i];
    }
}

__global__ __launch_bounds__(256) void fill_csr_kernel(const int* __restrict__ src,
                                                       const int* __restrict__ dst, int E,
                                                       int* __restrict__ fill,
                                                       int* __restrict__ col) {
    int e = blockIdx.x * 256 + threadIdx.x;
    if (e < E) {
        int d = dst[e];
        int pos = atomicAdd(&fill[d], 1);
        col[pos] = src[e];
    }
}

// ---------------- compute ----------------

// Out[row] = (X[row] @ W) * dinv[row];  X:[M,128], W:[128,128]
__global__ __launch_bounds__(256) void mm_scale_kernel(const float* __restrict__ X,
                                                       const float* __restrict__ W,
                                                       const float* __restrict__ dinv,
                                                       float* __restrict__ Out, int M) {
    __shared__ float xs[128 * 65];  // xs[k*65 + m] = X[row0+m][k], +1 pad vs 64
    int tid = threadIdx.x;
    int row0 = blockIdx.x * MM_ROWS;
    int c = tid & 31, rl = tid >> 5;
#pragma unroll
    for (int p = 0; p < MM_ROWS; p += 8) {
        int m = p + rl;
        int row = row0 + m;
        float4 v = make_float4(0.f, 0.f, 0.f, 0.f);
        if (row < M) v = *reinterpret_cast<const float4*>(X + (size_t)row * H + c * 4);
        xs[(4 * c + 0) * 65 + m] = v.x;
        xs[(4 * c + 1) * 65 + m] = v.y;
        xs[(4 * c + 2) * 65 + m] = v.z;
        xs[(4 * c + 3) * 65 + m] = v.w;
    }
    __syncthreads();
    int tx = tid & 31;  // cols 4*tx .. 4*tx+3
    int ty = tid >> 5;  // rows ty*8 .. ty*8+7
    float acc[8][4];
#pragma unroll
    for (int i = 0; i < 8; ++i)
#pragma unroll
        for (int j = 0; j < 4; ++j) acc[i][j] = 0.f;
#pragma unroll 4
    for (int k = 0; k < 128; ++k) {
        float4 w = *reinterpret_cast<const float4*>(W + k * H + tx * 4);
        float xv[8];
#pragma unroll
        for (int i = 0; i < 8; ++i) xv[i] = xs[k * 65 + ty * 8 + i];
#pragma unroll
        for (int i = 0; i < 8; ++i) {
            acc[i][0] = fmaf(xv[i], w.x, acc[i][0]);
            acc[i][1] = fmaf(xv[i], w.y, acc[i][1]);
            acc[i][2] = fmaf(xv[i], w.z, acc[i][2]);
            acc[i][3] = fmaf(xv[i], w.w, acc[i][3]);
        }
    }
#pragma unroll
    for (int i = 0; i < 8; ++i) {
        int row = row0 + ty * 8 + i;
        if (row < M) {
            float sc = dinv[row];
            float4 o = make_float4(acc[i][0] * sc, acc[i][1] * sc, acc[i][2] * sc,
                                   acc[i][3] * sc);
            *reinterpret_cast<float4*>(Out + (size_t)row * H + tx * 4) = o;
        }
    }
}

// Out[i] = relu(dinv[i] * (sum_{e in CSR row i} A[col[e]] + A[i]) + bias)
__global__ __launch_bounds__(128) void agg_kernel(const float* __restrict__ A,
                                                  const int* __restrict__ row_ptr,
                                                  const int* __restrict__ col,
                                                  const float* __restrict__ dinv,
                                                  const float* __restrict__ bias,
                                                  float* __restrict__ Out, int N) {
    int i = blockIdx.x;
    int f = threadIdx.x;
    int s = row_ptr[i], e = row_ptr[i + 1];
    float acc = A[(size_t)i * H + f];  // self-loop term (dinv factored out)
    int j = s;
    for (; j + 4 <= e; j += 4) {
        int c0 = col[j], c1 = col[j + 1], c2 = col[j + 2], c3 = col[j + 3];
        float a0 = A[(size_t)c0 * H + f];
        float a1 = A[(size_t)c1 * H + f];
        float a2 = A[(size_t)c2 * H + f];
        float a3 = A[(size_t)c3 * H + f];
        acc += a0;
        acc += a1;
        acc += a2;
        acc += a3;
    }
    for (; j < e; ++j) acc += A[(size_t)col[j] * H + f];
    float o = fmaf(dinv[i], acc, bias[f]);
    Out[(size_t)i * H + f] = fmaxf(o, 0.0f);
}

// ---------------- pooling (2-phase, parallel over nodes) ----------------

// Each block owns PCHUNK consecutive nodes; batch is sorted so the chunk spans
// few graphs. Threads own one feature; per-graph segment sums flushed via
// atomicAdd into gsum[g*H+f].
__global__ __launch_bounds__(128) void pool_partial(const float* __restrict__ Bm,
                                                    const int* __restrict__ batch,
                                                    float* __restrict__ gsum, int N) {
    __shared__ int sb[PCHUNK];
    int base = blockIdx.x * PCHUNK;
    int n_here = N - base;
    if (n_here > PCHUNK) n_here = PCHUNK;
    int f = threadIdx.x;
    if (f < n_here) sb[f] = batch[base + f];
    __syncthreads();
    float acc = 0.f;
    int cur = sb[0];
    for (int j = 0; j < n_here; ++j) {
        int g = sb[j];  // wave-uniform
        if (g != cur) {
            atomicAdd(&gsum[cur * H + f], acc);
            acc = 0.f;
            cur = g;
        }
        acc += Bm[(size_t)(base + j) * H + f];
    }
    atomicAdd(&gsum[cur * H + f], acc);
}

__global__ __launch_bounds__(128) void pool_final(const float* __restrict__ gsum,
                                                  const int* __restrict__ gstart,
                                                  float* __restrict__ g) {
    int gr = blockIdx.x, f = threadIdx.x;
    int cnt = gstart[gr + 1] - gstart[gr];
    g[gr * H + f] = gsum[gr * H + f] / fmaxf((float)cnt, 1.f);
}

__global__ __launch_bounds__(128) void head_kernel(const float* __restrict__ g,
                                                   const float* __restrict__ fW1,
                                                   const float* __restrict__ fb1,
                                                   const float* __restrict__ fW2,
                                                   const float* __restrict__ fb2,
                                                   float* __restrict__ out) {
    __shared__ float gv[H], hid[H], lg[DOUT];
    int gr = blockIdx.x, f = threadIdx.x;
    gv[f] = g[gr * H + f];
    __syncthreads();
    float acc = fb1[f];
    for (int k = 0; k < H; ++k) acc = fmaf(gv[k], fW1[k * H + f], acc);
    hid[f] = fmaxf(acc, 0.f);
    __syncthreads();
    if (f < DOUT) {
        float a = fb2[f];
        for (int k = 0; k < H; ++k) a = fmaf(hid[k], fW2[k * DOUT + f], a);
        lg[f] = a;
    }
    __syncthreads();
    if (f < DOUT) {
        float mx = -1e30f;
        for (int j = 0; j < DOUT; ++j) mx = fmaxf(mx, lg[j]);
        float ssum = 0.f;
        for (int j = 0; j < DOUT; ++j) ssum += expf(lg[j] - mx);
        out[gr * DOUT + f] = expf(lg[f] - mx) / ssum;
    }
}

// ---------------- launch ----------------

extern "C" void kernel_launch(void* const* d_in, const int* in_sizes, int n_in,
                              void* d_out, int out_size, void* d_ws, size_t ws_size,
                              hipStream_t stream) {
    const float* x = (const float*)d_in[0];
    const int* edge = (const int*)d_in[1];
    const int* batch = (const int*)d_in[2];
    const float* W1 = (const float*)d_in[3];
    const float* b1 = (const float*)d_in[4];
    const float* W2 = (const float*)d_in[5];
    const float* b2 = (const float*)d_in[6];
    const float* fW1 = (const float*)d_in[7];
    const float* fb1 = (const float*)d_in[8];
    const float* fW2 = (const float*)d_in[9];
    const float* fb2 = (const float*)d_in[10];
    float* out = (float*)d_out;

    int N = in_sizes[0] / H;
    int E = in_sizes[1] / 2;
    const int* srcI = edge;
    const int* dstI = edge + E;

    char* ws = (char*)d_ws;
    size_t off = 0;
    auto alloc = [&](size_t bytes) {
        void* p = ws + off;
        off = (off + bytes + 255) & ~(size_t)255;
        return p;
    };
    int* deg = (int*)alloc((size_t)N * 4);
    int* row_ptr = (int*)alloc((size_t)(N + 1) * 4);
    int* fill = (int*)alloc((size_t)N * 4);
    int* col = (int*)alloc((size_t)E * 4);
    float* dinv = (float*)alloc((size_t)N * 4);
    int* bsum = (int*)alloc(4096);
    int* gstart = (int*)alloc(512);
    float* gsum = (float*)alloc((size_t)NGRAPH * H * 4);
    float* gmat = (float*)alloc((size_t)NGRAPH * H * 4);
    float* A = (float*)alloc((size_t)N * H * 4);
    float* Bm = (float*)alloc((size_t)N * H * 4);
    (void)ws_size;

    hipMemsetAsync(deg, 0, (size_t)N * 4, stream);
    hipMemsetAsync(gsum, 0, (size_t)NGRAPH * H * 4, stream);

    int nb = (N + 1023) / 1024;
    hist_edge_kernel<<<(E + 255) / 256, 256, 0, stream>>>(dstI, E, deg);
    batch_bounds_kernel<<<(N + 255) / 256, 256, 0, stream>>>(batch, N, gstart);
    scan_phase1<<<nb, 256, 0, stream>>>(deg, N, bsum);
    scan_phase2<<<1, 1, 0, stream>>>(bsum, nb, row_ptr, N, E);
    scan_phase3<<<nb, 256, 0, stream>>>(deg, bsum, N, row_ptr);
    init_node_kernel<<<(N + 255) / 256, 256, 0, stream>>>(deg, row_ptr, dinv, fill, N);
    fill_csr_kernel<<<(E + 255) / 256, 256, 0, stream>>>(srcI, dstI, E, fill, col);

    int mmblocks = (N + MM_ROWS - 1) / MM_ROWS;
    mm_scale_kernel<<<mmblocks, 256, 0, stream>>>(x, W1, dinv, A, N);
    agg_kernel<<<N, 128, 0, stream>>>(A, row_ptr, col, dinv, b1, Bm, N);
    mm_scale_kernel<<<mmblocks, 256, 0, stream>>>(Bm, W2, dinv, A, N);
    agg_kernel<<<N, 128, 0, stream>>>(A, row_ptr, col, dinv, b2, Bm, N);
    pool_partial<<<(N + PCHUNK - 1) / PCHUNK, 128, 0, stream>>>(Bm, batch, gsum, N);
    pool_final<<<NGRAPH, 128, 0, stream>>>(gsum, gstart, gmat);
    head_kernel<<<NGRAPH, 128, 0, stream>>>(gmat, fW1, fb1, fW2, fb2, out);
}

// Round 4
// 555.321 us; speedup vs baseline: 2.6523x; 1.0825x over previous
//
#include <hip/hip_runtime.h>
#include <hip/hip_bf16.h>

#define H 128
#define DOUT 32
#define NGRAPH 64
#define MM_ROWS 64
#define PCHUNK 128
#define SORT_TILE 4096
#define NBUCK_MAX 128

// ---------------- edge bucket sort (by dst >> bshift) ----------------

__global__ __launch_bounds__(256) void bucket_hist_kernel(const int* __restrict__ dst, int E,
                                                          int bshift, int* __restrict__ bcnt) {
    __shared__ int lh[NBUCK_MAX];
    int t = threadIdx.x;
    if (t < NBUCK_MAX) lh[t] = 0;
    __syncthreads();
    int base = blockIdx.x * SORT_TILE;
    int cnt = E - base;
    if (cnt > SORT_TILE) cnt = SORT_TILE;
    for (int j = t; j < cnt; j += 256) atomicAdd(&lh[dst[base + j] >> bshift], 1);
    __syncthreads();
    if (t < NBUCK_MAX && lh[t]) atomicAdd(&bcnt[t], lh[t]);
}

__global__ void bucket_scan_kernel(const int* __restrict__ bcnt, int* __restrict__ bfill,
                                   int nbuck) {
    if (threadIdx.x == 0) {
        int run = 0;
        for (int b = 0; b < nbuck; ++b) {
            bfill[b] = run;
            run += bcnt[b];
        }
    }
}

// Bin a 4096-edge tile in LDS, reserve a contiguous global range per (block,bucket),
// write each bucket's run out coalesced.
__global__ __launch_bounds__(256) void bucket_scatter_kernel(const int* __restrict__ src,
                                                             const int* __restrict__ dst, int E,
                                                             int bshift, int* __restrict__ bfill,
                                                             int2* __restrict__ es) {
    __shared__ int lh[NBUCK_MAX], lsc[NBUCK_MAX], lbase[NBUCK_MAX], lfill[NBUCK_MAX],
        ldelta[NBUCK_MAX];
    __shared__ int2 sp[SORT_TILE];
    __shared__ unsigned char sb[SORT_TILE];
    int t = threadIdx.x;
    if (t < NBUCK_MAX) {
        lh[t] = 0;
        lfill[t] = 0;
    }
    __syncthreads();
    int base = blockIdx.x * SORT_TILE;
    int cnt = E - base;
    if (cnt > SORT_TILE) cnt = SORT_TILE;
    for (int j = t; j < cnt; j += 256) atomicAdd(&lh[dst[base + j] >> bshift], 1);
    __syncthreads();
    // exclusive scan of lh (128 entries, Hillis-Steele on first 128 threads)
    if (t < NBUCK_MAX) lsc[t] = lh[t];
    __syncthreads();
    for (int off = 1; off < NBUCK_MAX; off <<= 1) {
        int x = 0;
        if (t < NBUCK_MAX && t >= off) x = lsc[t - off];
        __syncthreads();
        if (t < NBUCK_MAX) lsc[t] += x;
        __syncthreads();
    }
    if (t < NBUCK_MAX) {
        lbase[t] = lsc[t] - lh[t];
        if (lh[t] > 0) ldelta[t] = atomicAdd(&bfill[t], lh[t]) - lbase[t];
    }
    __syncthreads();
    // place into LDS ordered by bucket
    for (int j = t; j < cnt; j += 256) {
        int s = src[base + j], d = dst[base + j];
        int b = d >> bshift;
        int r = atomicAdd(&lfill[b], 1);
        int slot = lbase[b] + r;
        sp[slot] = make_int2(s, d);
        sb[slot] = (unsigned char)b;
    }
    __syncthreads();
    // coalesced copy-out (runs of ~tile/nbuck consecutive elements per bucket)
    for (int j = t; j < cnt; j += 256) {
        int b = sb[j];
        es[ldelta[b] + j] = sp[j];
    }
}

// deg histogram over bucket-sorted edges: atomics land in a ~4KB window per wave
__global__ __launch_bounds__(256) void deg_hist_sorted(const int2* __restrict__ es, int E,
                                                       int* __restrict__ deg) {
    int e = blockIdx.x * 256 + threadIdx.x;
    if (e < E) atomicAdd(&deg[es[e].y], 1);
}

__global__ __launch_bounds__(256) void fill_csr_sorted(const int2* __restrict__ es, int E,
                                                       int* __restrict__ fill,
                                                       int* __restrict__ col) {
    int e = blockIdx.x * 256 + threadIdx.x;
    if (e < E) {
        int2 p = es[e];
        int pos = atomicAdd(&fill[p.y], 1);
        col[pos] = p.x;
    }
}

// ---------------- CSR row_ptr scan ----------------

// batch is sorted: gstart[g] = first index i with batch[i] >= g
__global__ __launch_bounds__(256) void batch_bounds_kernel(const int* __restrict__ batch,
                                                           int N, int* __restrict__ gstart) {
    int i = blockIdx.x * 256 + threadIdx.x;
    if (i < N) {
        int b = batch[i];
        int bp = (i == 0) ? -1 : batch[i - 1];
        for (int g = bp + 1; g <= b; ++g) gstart[g] = i;
        if (i == N - 1)
            for (int g = b + 1; g <= NGRAPH; ++g) gstart[g] = N;
    }
}

__global__ __launch_bounds__(256) void scan_phase1(const int* __restrict__ deg, int N,
                                                   int* __restrict__ bsum) {
    __shared__ int sd[256];
    int t = threadIdx.x;
    int base = blockIdx.x * 1024 + t * 4;
    int s = 0;
#pragma unroll
    for (int j = 0; j < 4; ++j)
        if (base + j < N) s += deg[base + j];
    sd[t] = s;
    __syncthreads();
    for (int off = 128; off > 0; off >>= 1) {
        if (t < off) sd[t] += sd[t + off];
        __syncthreads();
    }
    if (t == 0) bsum[blockIdx.x] = sd[0];
}

__global__ void scan_phase2(int* bsum, int nb, int* __restrict__ row_ptr, int N, int E) {
    if (threadIdx.x == 0) {
        int run = 0;
        for (int i = 0; i < nb; ++i) {
            int v = bsum[i];
            bsum[i] = run;
            run += v;
        }
        row_ptr[N] = E;
    }
}

__global__ __launch_bounds__(256) void scan_phase3(const int* __restrict__ deg,
                                                   const int* __restrict__ boff, int N,
                                                   int* __restrict__ row_ptr) {
    __shared__ int sd[256];
    int t = threadIdx.x;
    int base = blockIdx.x * 1024 + t * 4;
    int v[4];
    int s = 0;
#pragma unroll
    for (int j = 0; j < 4; ++j) {
        v[j] = (base + j < N) ? deg[base + j] : 0;
        s += v[j];
    }
    sd[t] = s;
    __syncthreads();
    for (int off = 1; off < 256; off <<= 1) {
        int x = (t >= off) ? sd[t - off] : 0;
        __syncthreads();
        sd[t] += x;
        __syncthreads();
    }
    int run = boff[blockIdx.x] + sd[t] - s;
#pragma unroll
    for (int j = 0; j < 4; ++j)
        if (base + j < N) {
            row_ptr[base + j] = run;
            run += v[j];
        }
}

__global__ __launch_bounds__(256) void init_node_kernel(const int* __restrict__ deg,
                                                        const int* __restrict__ row_ptr,
                                                        float* __restrict__ dinv,
                                                        int* __restrict__ fill, int N) {
    int i = blockIdx.x * 256 + threadIdx.x;
    if (i < N) {
        dinv[i] = rsqrtf(1.0f + (float)deg[i]);
        fill[i] = row_ptr[i];
    }
}

// ---------------- compute ----------------

// Out[row] = (X[row] @ W) * dinv[row];  X:[M,128], W:[128,128]
__global__ __launch_bounds__(256) void mm_scale_kernel(const float* __restrict__ X,
                                                       const float* __restrict__ W,
                                                       const float* __restrict__ dinv,
                                                       float* __restrict__ Out, int M) {
    __shared__ float xs[128 * 65];
    int tid = threadIdx.x;
    int row0 = blockIdx.x * MM_ROWS;
    int c = tid & 31, rl = tid >> 5;
#pragma unroll
    for (int p = 0; p < MM_ROWS; p += 8) {
        int m = p + rl;
        int row = row0 + m;
        float4 v = make_float4(0.f, 0.f, 0.f, 0.f);
        if (row < M) v = *reinterpret_cast<const float4*>(X + (size_t)row * H + c * 4);
        xs[(4 * c + 0) * 65 + m] = v.x;
        xs[(4 * c + 1) * 65 + m] = v.y;
        xs[(4 * c + 2) * 65 + m] = v.z;
        xs[(4 * c + 3) * 65 + m] = v.w;
    }
    __syncthreads();
    int tx = tid & 31;
    int ty = tid >> 5;
    float acc[8][4];
#pragma unroll
    for (int i = 0; i < 8; ++i)
#pragma unroll
        for (int j = 0; j < 4; ++j) acc[i][j] = 0.f;
#pragma unroll 4
    for (int k = 0; k < 128; ++k) {
        float4 w = *reinterpret_cast<const float4*>(W + k * H + tx * 4);
        float xv[8];
#pragma unroll
        for (int i = 0; i < 8; ++i) xv[i] = xs[k * 65 + ty * 8 + i];
#pragma unroll
        for (int i = 0; i < 8; ++i) {
            acc[i][0] = fmaf(xv[i], w.x, acc[i][0]);
            acc[i][1] = fmaf(xv[i], w.y, acc[i][1]);
            acc[i][2] = fmaf(xv[i], w.z, acc[i][2]);
            acc[i][3] = fmaf(xv[i], w.w, acc[i][3]);
        }
    }
#pragma unroll
    for (int i = 0; i < 8; ++i) {
        int row = row0 + ty * 8 + i;
        if (row < M) {
            float sc = dinv[row];
            float4 o = make_float4(acc[i][0] * sc, acc[i][1] * sc, acc[i][2] * sc,
                                   acc[i][3] * sc);
            *reinterpret_cast<float4*>(Out + (size_t)row * H + tx * 4) = o;
        }
    }
}

// Out[i] = relu(dinv[i] * (sum_{e in CSR row i} A[col[e]] + A[i]) + bias)
__global__ __launch_bounds__(128) void agg_kernel(const float* __restrict__ A,
                                                  const int* __restrict__ row_ptr,
                                                  const int* __restrict__ col,
                                                  const float* __restrict__ dinv,
                                                  const float* __restrict__ bias,
                                                  float* __restrict__ Out, int N) {
    int i = blockIdx.x;
    int f = threadIdx.x;
    int s = row_ptr[i], e = row_ptr[i + 1];
    float acc = A[(size_t)i * H + f];
    int j = s;
    for (; j + 4 <= e; j += 4) {
        int c0 = col[j], c1 = col[j + 1], c2 = col[j + 2], c3 = col[j + 3];
        float a0 = A[(size_t)c0 * H + f];
        float a1 = A[(size_t)c1 * H + f];
        float a2 = A[(size_t)c2 * H + f];
        float a3 = A[(size_t)c3 * H + f];
        acc += a0;
        acc += a1;
        acc += a2;
        acc += a3;
    }
    for (; j < e; ++j) acc += A[(size_t)col[j] * H + f];
    float o = fmaf(dinv[i], acc, bias[f]);
    Out[(size_t)i * H + f] = fmaxf(o, 0.0f);
}

// ---------------- pooling ----------------

__global__ __launch_bounds__(128) void pool_partial(const float* __restrict__ Bm,
                                                    const int* __restrict__ batch,
                                                    float* __restrict__ gsum, int N) {
    __shared__ int sb[PCHUNK];
    int base = blockIdx.x * PCHUNK;
    int n_here = N - base;
    if (n_here > PCHUNK) n_here = PCHUNK;
    int f = threadIdx.x;
    if (f < n_here) sb[f] = batch[base + f];
    __syncthreads();
    float acc = 0.f;
    int cur = sb[0];
    for (int j = 0; j < n_here; ++j) {
        int g = sb[j];
        if (g != cur) {
            atomicAdd(&gsum[cur * H + f], acc);
            acc = 0.f;
            cur = g;
        }
        acc += Bm[(size_t)(base + j) * H + f];
    }
    atomicAdd(&gsum[cur * H + f], acc);
}

__global__ __launch_bounds__(128) void pool_final(const float* __restrict__ gsum,
                                                  const int* __restrict__ gstart,
                                                  float* __restrict__ g) {
    int gr = blockIdx.x, f = threadIdx.x;
    int cnt = gstart[gr + 1] - gstart[gr];
    g[gr * H + f] = gsum[gr * H + f] / fmaxf((float)cnt, 1.f);
}

__global__ __launch_bounds__(128) void head_kernel(const float* __restrict__ g,
                                                   const float* __restrict__ fW1,
                                                   const float* __restrict__ fb1,
                                                   const float* __restrict__ fW2,
                                                   const float* __restrict__ fb2,
                                                   float* __restrict__ out) {
    __shared__ float gv[H], hid[H], lg[DOUT];
    int gr = blockIdx.x, f = threadIdx.x;
    gv[f] = g[gr * H + f];
    __syncthreads();
    float acc = fb1[f];
    for (int k = 0; k < H; ++k) acc = fmaf(gv[k], fW1[k * H + f], acc);
    hid[f] = fmaxf(acc, 0.f);
    __syncthreads();
    if (f < DOUT) {
        float a = fb2[f];
        for (int k = 0; k < H; ++k) a = fmaf(hid[k], fW2[k * DOUT + f], a);
        lg[f] = a;
    }
    __syncthreads();
    if (f < DOUT) {
        float mx = -1e30f;
        for (int j = 0; j < DOUT; ++j) mx = fmaxf(mx, lg[j]);
        float ssum = 0.f;
        for (int j = 0; j < DOUT; ++j) ssum += expf(lg[j] - mx);
        out[gr * DOUT + f] = expf(lg[f] - mx) / ssum;
    }
}

// ---------------- launch ----------------

extern "C" void kernel_launch(void* const* d_in, const int* in_sizes, int n_in,
                              void* d_out, int out_size, void* d_ws, size_t ws_size,
                              hipStream_t stream) {
    const float* x = (const float*)d_in[0];
    const int* edge = (const int*)d_in[1];
    const int* batch = (const int*)d_in[2];
    const float* W1 = (const float*)d_in[3];
    const float* b1 = (const float*)d_in[4];
    const float* W2 = (const float*)d_in[5];
    const float* b2 = (const float*)d_in[6];
    const float* fW1 = (const float*)d_in[7];
    const float* fb1 = (const float*)d_in[8];
    const float* fW2 = (const float*)d_in[9];
    const float* fb2 = (const float*)d_in[10];
    float* out = (float*)d_out;

    int N = in_sizes[0] / H;
    int E = in_sizes[1] / 2;
    const int* srcI = edge;
    const int* dstI = edge + E;

    char* ws = (char*)d_ws;
    size_t off = 0;
    auto alloc = [&](size_t bytes) {
        void* p = ws + off;
        off = (off + bytes + 255) & ~(size_t)255;
        return p;
    };
    int* deg = (int*)alloc((size_t)N * 4);
    int* row_ptr = (int*)alloc((size_t)(N + 1) * 4);
    int* fill = (int*)alloc((size_t)N * 4);
    int* col = (int*)alloc((size_t)E * 4);
    float* dinv = (float*)alloc((size_t)N * 4);
    int* bsum = (int*)alloc(4096);
    int* gstart = (int*)alloc(512);
    int* bcnt = (int*)alloc(NBUCK_MAX * 4);
    int* bfill = (int*)alloc(NBUCK_MAX * 4);
    float* gsum = (float*)alloc((size_t)NGRAPH * H * 4);
    float* gmat = (float*)alloc((size_t)NGRAPH * H * 4);
    float* A = (float*)alloc((size_t)N * H * 4);
    float* Bm = (float*)alloc((size_t)N * H * 4);
    (void)ws_size;

    // es (sorted edges, E*8B) aliases A: consumed by fill_csr_sorted before
    // mm_scale writes A; same stream -> serial -> safe.
    int2* es = (int2*)A;

    // bucket shift: nbuck = ceil(N / 2^bshift) <= 128
    int bshift = 0;
    while (((N - 1) >> bshift) >= NBUCK_MAX) ++bshift;
    int nbuck = ((N - 1) >> bshift) + 1;

    hipMemsetAsync(deg, 0, (size_t)N * 4, stream);
    hipMemsetAsync(bcnt, 0, NBUCK_MAX * 4, stream);
    hipMemsetAsync(gsum, 0, (size_t)NGRAPH * H * 4, stream);

    int nb = (N + 1023) / 1024;
    int nst = (E + SORT_TILE - 1) / SORT_TILE;

    bucket_hist_kernel<<<nst, 256, 0, stream>>>(dstI, E, bshift, bcnt);
    bucket_scan_kernel<<<1, 1, 0, stream>>>(bcnt, bfill, nbuck);
    bucket_scatter_kernel<<<nst, 256, 0, stream>>>(srcI, dstI, E, bshift, bfill, es);
    deg_hist_sorted<<<(E + 255) / 256, 256, 0, stream>>>(es, E, deg);

    batch_bounds_kernel<<<(N + 255) / 256, 256, 0, stream>>>(batch, N, gstart);
    scan_phase1<<<nb, 256, 0, stream>>>(deg, N, bsum);
    scan_phase2<<<1, 1, 0, stream>>>(bsum, nb, row_ptr, N, E);
    scan_phase3<<<nb, 256, 0, stream>>>(deg, bsum, N, row_ptr);
    init_node_kernel<<<(N + 255) / 256, 256, 0, stream>>>(deg, row_ptr, dinv, fill, N);
    fill_csr_sorted<<<(E + 255) / 256, 256, 0, stream>>>(es, E, fill, col);

    int mmblocks = (N + MM_ROWS - 1) / MM_ROWS;
    mm_scale_kernel<<<mmblocks, 256, 0, stream>>>(x, W1, dinv, A, N);
    agg_kernel<<<N, 128, 0, stream>>>(A, row_ptr, col, dinv, b1, Bm, N);
    mm_scale_kernel<<<mmblocks, 256, 0, stream>>>(Bm, W2, dinv, A, N);
    agg_kernel<<<N, 128, 0, stream>>>(A, row_ptr, col, dinv, b2, Bm, N);
    pool_partial<<<(N + PCHUNK - 1) / PCHUNK, 128, 0, stream>>>(Bm, batch, gsum, N);
    pool_final<<<NGRAPH, 128, 0, stream>>>(gsum, gstart, gmat);
    head_kernel<<<NGRAPH, 128, 0, stream>>>(gmat, fW1, fb1, fW2, fb2, out);
}